// Round 1
// baseline (245.539 us; speedup 1.0000x reference)
//
#include <hip/hip_runtime.h>
#include <hip/hip_bf16.h>

#define BSZ 256
#define ADIM 128
#define HID 512
#define TI 8
#define TJ 8
#define MT 64          // pair-rows per block
#define LDH 520        // padded LDS row stride in bf16 elements (2-way bank alias on b128 reads = free)

typedef __attribute__((ext_vector_type(8))) short short8;
typedef __attribute__((ext_vector_type(4))) float float4_t;

__device__ inline short f32_to_bf16_bits(float f) {
    union { float f; unsigned u; } v; v.f = f;
    unsigned u = v.u;
    unsigned r = u + 0x7FFFu + ((u >> 16) & 1u);   // RNE
    return (short)(r >> 16);
}
__device__ inline float bf16_bits_to_f32(short s) {
    union { unsigned u; float f; } v;
    v.u = ((unsigned)(unsigned short)s) << 16;
    return v.f;
}

// ---------------- prep: hx = x@Wx + b0, hy = y@Wy (f32); W1t/W2t = bf16 transpose ----
__global__ void prep_kernel(const float* __restrict__ x, const float* __restrict__ y,
                            const float* __restrict__ Wx, const float* __restrict__ Wy,
                            const float* __restrict__ b0, const float* __restrict__ W1,
                            const float* __restrict__ W2,
                            float* __restrict__ hx, float* __restrict__ hy,
                            short* __restrict__ W1t, short* __restrict__ W2t) {
    const int N_H = BSZ * HID;   // 131072
    const int N_W = HID * HID;   // 262144
    int t = blockIdx.x * blockDim.x + threadIdx.x;
    if (t < N_H) {
        int i = t >> 9, h = t & 511;
        float s = b0[h];
        const float* xr = x + i * ADIM;
        const float* wc = Wx + h;
        for (int k = 0; k < ADIM; ++k) s = fmaf(xr[k], wc[k * HID], s);
        hx[t] = s;
    } else if (t < 2 * N_H) {
        int tt = t - N_H;
        int i = tt >> 9, h = tt & 511;
        float s = 0.f;
        const float* yr = y + i * ADIM;
        const float* wc = Wy + h;
        for (int k = 0; k < ADIM; ++k) s = fmaf(yr[k], wc[k * HID], s);
        hy[tt] = s;
    } else if (t < 2 * N_H + N_W) {
        int tt = t - 2 * N_H;
        int n = tt >> 9, k = tt & 511;
        W1t[tt] = f32_to_bf16_bits(W1[k * HID + n]);
    } else if (t < 2 * N_H + 2 * N_W) {
        int tt = t - 2 * N_H - N_W;
        int n = tt >> 9, k = tt & 511;
        W2t[tt] = f32_to_bf16_bits(W2[k * HID + n]);
    }
}

// ---------------- one fused 512->512 layer: D = relu(A @ W^T? no: A[M,K] @ W[K,N] + b), W given transposed [N,K]
__device__ inline void gemm_layer(const short* __restrict__ As, const short* __restrict__ Wt,
                                  const float* __restrict__ bias, short* __restrict__ Ds,
                                  int wave, int lane) {
    const int quad = lane >> 4;
    const int lq = lane & 15;
    const int n0 = wave * 64;

    float4_t acc[4][4];
    #pragma unroll
    for (int mi = 0; mi < 4; ++mi)
        #pragma unroll
        for (int ni = 0; ni < 4; ++ni)
            acc[mi][ni] = (float4_t){0.f, 0.f, 0.f, 0.f};

    const short* wbase = Wt + (n0 + lq) * HID + quad * 8;
    const short* abase = As + lq * LDH + quad * 8;

    #pragma unroll 2
    for (int k0 = 0; k0 < HID; k0 += 32) {
        short8 bf[4], af[4];
        #pragma unroll
        for (int ni = 0; ni < 4; ++ni)
            bf[ni] = *(const short8*)(wbase + ni * 16 * HID + k0);
        #pragma unroll
        for (int mi = 0; mi < 4; ++mi)
            af[mi] = *(const short8*)(abase + mi * 16 * LDH + k0);
        #pragma unroll
        for (int mi = 0; mi < 4; ++mi)
            #pragma unroll
            for (int ni = 0; ni < 4; ++ni)
                acc[mi][ni] = __builtin_amdgcn_mfma_f32_16x16x32_bf16(
                    af[mi], bf[ni], acc[mi][ni], 0, 0, 0);
    }

    // epilogue: +bias, relu, bf16, store to LDS
    #pragma unroll
    for (int ni = 0; ni < 4; ++ni) {
        float bv = bias[n0 + ni * 16 + lq];
        #pragma unroll
        for (int mi = 0; mi < 4; ++mi) {
            #pragma unroll
            for (int r = 0; r < 4; ++r) {
                float v = acc[mi][ni][r] + bv;
                v = fmaxf(v, 0.f);
                Ds[(mi * 16 + quad * 4 + r) * LDH + n0 + ni * 16 + lq] = f32_to_bf16_bits(v);
            }
        }
    }
}

__global__ __launch_bounds__(512, 2) void critic_kernel(
    const float* __restrict__ hx, const float* __restrict__ hy,
    const short* __restrict__ W1t, const short* __restrict__ W2t,
    const float* __restrict__ b1, const float* __restrict__ b2,
    const float* __restrict__ W3, const float* __restrict__ b3,
    float* __restrict__ out) {
    __shared__ short h0s[MT * LDH];   // 66,560 B
    __shared__ short h1s[MT * LDH];   // 66,560 B
    __shared__ float psum[512];       // 2,048 B  (total 135,168 < 160 KiB)

    const int tid = threadIdx.x;
    const int wave = tid >> 6;
    const int lane = tid & 63;

    const int i0 = (blockIdx.x >> 5) * TI;
    const int j0 = (blockIdx.x & 31) * TJ;

    // ---- build h0 = relu(hx[i] + hy[j]) as bf16 in LDS (b0 folded into hx) ----
    for (int e = tid; e < MT * 64; e += 512) {
        int r = e >> 6;              // 0..63
        int ko = (e & 63) * 8;       // 0..504
        int ti = r >> 3, tj = r & 7;
        const float4_t* px = (const float4_t*)(hx + (i0 + ti) * HID + ko);
        const float4_t* py = (const float4_t*)(hy + (j0 + tj) * HID + ko);
        float4_t a0 = px[0], a1 = px[1];
        float4_t c0 = py[0], c1 = py[1];
        short8 v;
        #pragma unroll
        for (int u = 0; u < 4; ++u) v[u]     = f32_to_bf16_bits(fmaxf(a0[u] + c0[u], 0.f));
        #pragma unroll
        for (int u = 0; u < 4; ++u) v[4 + u] = f32_to_bf16_bits(fmaxf(a1[u] + c1[u], 0.f));
        *(short8*)(h0s + r * LDH + ko) = v;
    }
    __syncthreads();

    // ---- layer1: h1 = relu(h0 @ W1 + b1) ----
    gemm_layer(h0s, W1t, b1, h1s, wave, lane);
    __syncthreads();

    // ---- layer2: h2 = relu(h1 @ W2 + b2), reuse h0 buffer ----
    gemm_layer(h1s, W2t, b2, h0s, wave, lane);
    __syncthreads();

    // ---- final: out = h2 @ W3 + b3 ----
    {
        int r = tid >> 3;            // 0..63
        int oc = (tid & 7) * 64;     // k chunk
        const short* hrow = h0s + r * LDH + oc;
        float s = 0.f;
        for (int k = 0; k < 64; k += 8) {
            short8 v = *(const short8*)(hrow + k);
            #pragma unroll
            for (int u = 0; u < 8; ++u)
                s = fmaf(bf16_bits_to_f32(v[u]), W3[oc + k + u], s);
        }
        psum[tid] = s;
    }
    __syncthreads();
    if (tid < 64) {
        float s = b3[0];
        #pragma unroll
        for (int o = 0; o < 8; ++o) s += psum[tid * 8 + o];
        int ti = tid >> 3, tj = tid & 7;
        out[(i0 + ti) * BSZ + (j0 + tj)] = s;
    }
}

extern "C" void kernel_launch(void* const* d_in, const int* in_sizes, int n_in,
                              void* d_out, int out_size, void* d_ws, size_t ws_size,
                              hipStream_t stream) {
    const float* x  = (const float*)d_in[0];
    const float* y  = (const float*)d_in[1];
    const float* Wx = (const float*)d_in[2];
    const float* Wy = (const float*)d_in[3];
    const float* b0 = (const float*)d_in[4];
    const float* W1 = (const float*)d_in[5];
    const float* b1 = (const float*)d_in[6];
    const float* W2 = (const float*)d_in[7];
    const float* b2 = (const float*)d_in[8];
    const float* W3 = (const float*)d_in[9];
    const float* b3 = (const float*)d_in[10];
    float* out = (float*)d_out;

    char* ws = (char*)d_ws;
    float* hx  = (float*)(ws);                  // 512 KB
    float* hy  = (float*)(ws + 512 * 1024);     // 512 KB
    short* W1t = (short*)(ws + 1024 * 1024);    // 512 KB
    short* W2t = (short*)(ws + 1536 * 1024);    // 512 KB (2 MB total)

    const int prep_items = 2 * BSZ * HID + 2 * HID * HID;   // 786432
    prep_kernel<<<(prep_items + 255) / 256, 256, 0, stream>>>(
        x, y, Wx, Wy, b0, W1, W2, hx, hy, W1t, W2t);

    critic_kernel<<<1024, 512, 0, stream>>>(hx, hy, W1t, W2t, b1, b2, W3, b3, out);
}

// Round 2
// 217.008 us; speedup vs baseline: 1.1315x; 1.1315x over previous
//
#include <hip/hip_runtime.h>
#include <hip/hip_bf16.h>

#define BSZ 256
#define ADIM 128
#define HID 512
#define TI 8
#define TJ 8
#define MT 64          // pair-rows per block
#define LDH 520        // padded LDS row stride in bf16 elements

typedef __attribute__((ext_vector_type(8))) short short8;
typedef __attribute__((ext_vector_type(4))) float float4_t;

__device__ inline short f32_to_bf16_bits(float f) {
    union { float f; unsigned u; } v; v.f = f;
    unsigned u = v.u;
    unsigned r = u + 0x7FFFu + ((u >> 16) & 1u);   // RNE
    return (short)(r >> 16);
}
__device__ inline float bf16_bits_to_f32(short s) {
    union { unsigned u; float f; } v;
    v.u = ((unsigned)(unsigned short)s) << 16;
    return v.f;
}

// ---------------- prep (256 blocks x 512 threads) ----------------
// blocks [0,64):    hx = x@Wx + b0   (4 rows per block)
// blocks [64,128):  hy = y@Wy        (4 rows per block)
// blocks [128,192): W1t = bf16(W1^T) (64x64 tile per block)
// blocks [192,256): W2t = bf16(W2^T)
__global__ __launch_bounds__(512) void prep_kernel(
        const float* __restrict__ x, const float* __restrict__ y,
        const float* __restrict__ Wx, const float* __restrict__ Wy,
        const float* __restrict__ b0, const float* __restrict__ W1,
        const float* __restrict__ W2,
        float* __restrict__ hx, float* __restrict__ hy,
        short* __restrict__ W1t, short* __restrict__ W2t) {
    __shared__ float lds[64 * 65];          // 16.6 KB, shared across both paths
    const int tid = threadIdx.x;
    const int bid = blockIdx.x;

    if (bid < 128) {
        // ---- GEMV path: 4 rows of hx or hy ----
        const bool isX = bid < 64;
        const int i0 = (isX ? bid : bid - 64) * 4;      // first row
        const float* src = isX ? x : y;
        const float* W   = isX ? Wx : Wy;
        float* dst       = isX ? hx : hy;

        // load 4 input rows (512 consecutive floats) into LDS
        lds[tid] = src[i0 * ADIM + tid];
        __syncthreads();

        const int h = tid;
        float s0 = 0.f, s1 = 0.f, s2 = 0.f, s3 = 0.f;
        const float* wcol = W + h;
        #pragma unroll 8
        for (int k = 0; k < ADIM; ++k) {
            float w = wcol[k * HID];
            s0 = fmaf(lds[k], w, s0);
            s1 = fmaf(lds[ADIM + k], w, s1);
            s2 = fmaf(lds[2 * ADIM + k], w, s2);
            s3 = fmaf(lds[3 * ADIM + k], w, s3);
        }
        float bb = isX ? b0[h] : 0.f;
        dst[(i0 + 0) * HID + h] = s0 + bb;
        dst[(i0 + 1) * HID + h] = s1 + bb;
        dst[(i0 + 2) * HID + h] = s2 + bb;
        dst[(i0 + 3) * HID + h] = s3 + bb;
    } else {
        // ---- transpose path: one 64x64 tile ----
        const int tb = bid - 128;
        const bool is1 = tb < 64;
        const int t8 = is1 ? tb : tb - 64;
        const float* Wsrc = is1 ? W1 : W2;
        short* Wdst = is1 ? W1t : W2t;
        const int k0 = (t8 >> 3) * 64;      // source row block
        const int n0 = (t8 & 7) * 64;       // source col block

        #pragma unroll
        for (int i = 0; i < 8; ++i) {
            int r = (tid >> 6) + i * 8;     // source row within tile
            int c = tid & 63;               // source col within tile (coalesced)
            lds[c * 65 + r] = Wsrc[(k0 + r) * HID + n0 + c];
        }
        __syncthreads();
        #pragma unroll
        for (int i = 0; i < 8; ++i) {
            int n = (tid >> 6) + i * 8;
            int k = tid & 63;               // coalesced write
            Wdst[(n0 + n) * HID + k0 + k] = f32_to_bf16_bits(lds[n * 65 + k]);
        }
    }
}

// ---------------- fused layer: acc in regs, single LDS buffer ----------------
// Phase 1 (reads hs + global Wt) -> barrier -> phase 2 (write relu bf16 to hs)
__device__ inline void gemm_layer(short* __restrict__ hs, const short* __restrict__ Wt,
                                  const float* __restrict__ bias,
                                  int wave, int lane) {
    const int quad = lane >> 4;
    const int lq = lane & 15;
    const int n0 = wave * 64;

    float4_t acc[4][4];
    #pragma unroll
    for (int mi = 0; mi < 4; ++mi)
        #pragma unroll
        for (int ni = 0; ni < 4; ++ni)
            acc[mi][ni] = (float4_t){0.f, 0.f, 0.f, 0.f};

    const short* wbase = Wt + (n0 + lq) * HID + quad * 8;
    const short* abase = hs + lq * LDH + quad * 8;

    #pragma unroll 2
    for (int k0 = 0; k0 < HID; k0 += 32) {
        short8 bf[4], af[4];
        #pragma unroll
        for (int ni = 0; ni < 4; ++ni)
            bf[ni] = *(const short8*)(wbase + ni * 16 * HID + k0);
        #pragma unroll
        for (int mi = 0; mi < 4; ++mi)
            af[mi] = *(const short8*)(abase + mi * 16 * LDH + k0);
        #pragma unroll
        for (int mi = 0; mi < 4; ++mi)
            #pragma unroll
            for (int ni = 0; ni < 4; ++ni)
                acc[mi][ni] = __builtin_amdgcn_mfma_f32_16x16x32_bf16(
                    af[mi], bf[ni], acc[mi][ni], 0, 0, 0);
    }

    float bv[4];
    #pragma unroll
    for (int ni = 0; ni < 4; ++ni) bv[ni] = bias[n0 + ni * 16 + lq];

    __syncthreads();   // all reads of hs complete before overwrite

    #pragma unroll
    for (int ni = 0; ni < 4; ++ni) {
        #pragma unroll
        for (int mi = 0; mi < 4; ++mi) {
            #pragma unroll
            for (int r = 0; r < 4; ++r) {
                float v = acc[mi][ni][r] + bv[ni];
                v = fmaxf(v, 0.f);
                hs[(mi * 16 + quad * 4 + r) * LDH + n0 + ni * 16 + lq] = f32_to_bf16_bits(v);
            }
        }
    }
    __syncthreads();
}

__global__ __launch_bounds__(512, 4) void critic_kernel(
    const float* __restrict__ hx, const float* __restrict__ hy,
    const short* __restrict__ W1t, const short* __restrict__ W2t,
    const float* __restrict__ b1, const float* __restrict__ b2,
    const float* __restrict__ W3, const float* __restrict__ b3,
    float* __restrict__ out) {
    __shared__ short hs[MT * LDH];   // 66,560 B
    __shared__ float psum[512];      // 2,048 B  (total 68,608 -> 2 blocks/CU)

    const int tid = threadIdx.x;
    const int wave = tid >> 6;
    const int lane = tid & 63;

    const int i0 = (blockIdx.x >> 5) * TI;
    const int j0 = (blockIdx.x & 31) * TJ;

    // ---- h0 = relu(hx[i] + hy[j]) bf16 in LDS (b0 folded into hx) ----
    #pragma unroll
    for (int e = tid; e < MT * 64; e += 512) {
        int r = e >> 6;              // row (i,j pair)
        int ko = (e & 63) * 8;       // 8-elem chunk
        int ti = r >> 3, tj = r & 7;
        const float4_t* px = (const float4_t*)(hx + (i0 + ti) * HID + ko);
        const float4_t* py = (const float4_t*)(hy + (j0 + tj) * HID + ko);
        float4_t a0 = px[0], a1 = px[1];
        float4_t c0 = py[0], c1 = py[1];
        short8 v;
        #pragma unroll
        for (int u = 0; u < 4; ++u) v[u]     = f32_to_bf16_bits(fmaxf(a0[u] + c0[u], 0.f));
        #pragma unroll
        for (int u = 0; u < 4; ++u) v[4 + u] = f32_to_bf16_bits(fmaxf(a1[u] + c1[u], 0.f));
        *(short8*)(hs + r * LDH + ko) = v;
    }
    __syncthreads();

    gemm_layer(hs, W1t, b1, wave, lane);   // h1 = relu(h0 @ W1 + b1)
    gemm_layer(hs, W2t, b2, wave, lane);   // h2 = relu(h1 @ W2 + b2)

    // ---- final: out = h2 @ W3 + b3 ----
    {
        int r = tid >> 3;            // row 0..63
        int oc = (tid & 7) * 64;     // k chunk
        const short* hrow = hs + r * LDH + oc;
        float s = 0.f;
        #pragma unroll
        for (int k = 0; k < 64; k += 8) {
            short8 v = *(const short8*)(hrow + k);
            #pragma unroll
            for (int u = 0; u < 8; ++u)
                s = fmaf(bf16_bits_to_f32(v[u]), W3[oc + k + u], s);
        }
        psum[tid] = s;
    }
    __syncthreads();
    if (tid < 64) {
        float s = b3[0];
        #pragma unroll
        for (int o = 0; o < 8; ++o) s += psum[tid * 8 + o];
        int ti = tid >> 3, tj = tid & 7;
        out[(i0 + ti) * BSZ + (j0 + tj)] = s;
    }
}

extern "C" void kernel_launch(void* const* d_in, const int* in_sizes, int n_in,
                              void* d_out, int out_size, void* d_ws, size_t ws_size,
                              hipStream_t stream) {
    const float* x  = (const float*)d_in[0];
    const float* y  = (const float*)d_in[1];
    const float* Wx = (const float*)d_in[2];
    const float* Wy = (const float*)d_in[3];
    const float* b0 = (const float*)d_in[4];
    const float* W1 = (const float*)d_in[5];
    const float* b1 = (const float*)d_in[6];
    const float* W2 = (const float*)d_in[7];
    const float* b2 = (const float*)d_in[8];
    const float* W3 = (const float*)d_in[9];
    const float* b3 = (const float*)d_in[10];
    float* out = (float*)d_out;

    char* ws = (char*)d_ws;
    float* hx  = (float*)(ws);                  // 512 KB
    float* hy  = (float*)(ws + 512 * 1024);     // 512 KB
    short* W1t = (short*)(ws + 1024 * 1024);    // 512 KB
    short* W2t = (short*)(ws + 1536 * 1024);    // 512 KB

    prep_kernel<<<256, 512, 0, stream>>>(x, y, Wx, Wy, b0, W1, W2, hx, hy, W1t, W2t);
    critic_kernel<<<1024, 512, 0, stream>>>(hx, hy, W1t, W2t, b1, b2, W3, b3, out);
}